// Round 12
// baseline (51.486 us; speedup 1.0000x reference)
//
#include <hip/hip_runtime.h>
#include <math.h>

#define HS 64
#define WS 208
#define HF 128
#define WF 416
#define NS (HS * WS)   // 13312
#define KH 20
#define KS 41
#define KK (KS * KS)   // 1681
#define TW 8           // tile width in pixels
#define TH 8           // tile height in pixels
#define NBX (WS / TW)  // 26
#define NBY (HS / TH)  // 8
#define NBLK (NBX * NBY) // 208
#define TROW 48        // union rows staged
#define TCOL 48        // union cols staged
#define PITCH 49       // float4 row pitch
#define GEL (KS * TCOL) // per-wave element set: 41 rows x 48 cols = 1968
#define NIT 31         // 1968 = 30*64 + 48 -> 31 iters, last has 48 lanes
#define LOG2E 1.442695040888963f

// align_corners grid: f32 coords exactly as _resize_ac (arange(f32) * (f32(in-1)/f32(out-1))).
__device__ __forceinline__ void ac_idx(int o, int inN, float sc, int& i0, int& i1, float& w) {
#pragma clang fp contract(off)
    float s = (float)o * sc;
    float f = floorf(s);
    i0 = (int)f;
    i1 = min(i0 + 1, inN - 1);
    w = s - f;
}

// Fused kernel: one block per 8x8 pixel tile; one WAVE per pixel-row (8 pixels).
// Each ray element is read from LDS ONCE per wave and dotted against all 8 pixel
// directions (in VGPRs) -> 8x less LDS traffic than the slice scheme.
__global__ __launch_bounds__(512, 2) void k_fused(const float* __restrict__ R,
                                                  const float* __restrict__ X,
                                                  const int* __restrict__ prog,
                                                  float* __restrict__ xn,
                                                  float* __restrict__ yn) {
#pragma clang fp contract(off)
    __shared__ float4 tile[TROW * PITCH];
    __shared__ float4 dirs[64];
    __shared__ float Tsh;

    int t = (int)threadIdx.x;
    int lane = t & 63;
    int py = t >> 6;                       // wave index == pixel row within tile
    int blk = (int)blockIdx.x;
    int by = blk / NBX, bx = blk - by * NBX;
    int ph0 = by * TH, pw0 = bx * TW;
    int srow_min = min(max(ph0 - KH, 0), HS - 1 - 2 * KH);
    int scol_min = min(max(pw0 - KH, 0), WS - 1 - 2 * KH);

    // ---- stage ray union tile (bit-exact f32 resize of R, mul/mul/add, no FMA) ----
    for (int e = t; e < TROW * TCOL; e += 512) {
        int i = e / TCOL, j = e - i * TCOL;
        int g = srow_min + i, cg = scol_min + j;
        if (g < HS && cg < WS) {
            int y0, y1, x0, x1; float wy, wx;
            ac_idx(g, HF, 127.0f / 63.0f, y0, y1, wy);
            ac_idx(cg, WF, 415.0f / 207.0f, x0, x1, wx);
            float omwy = 1.0f - wy, omwx = 1.0f - wx;
            float r[3];
#pragma unroll
            for (int c = 0; c < 3; ++c) {
                const float* p = R + c * (HF * WF);
                float v00 = p[y0 * WF + x0], v10 = p[y1 * WF + x0];
                float v01 = p[y0 * WF + x1], v11 = p[y1 * WF + x1];
                float a0 = v00 * omwy; float b0 = v10 * wy; float t0 = a0 + b0;
                float a1 = v01 * omwy; float b1 = v11 * wy; float t1 = a1 + b1;
                float c0 = t0 * omwx; float c1 = t1 * wx;
                r[c] = c0 + c1;
            }
            tile[i * PITCH + j] = make_float4(r[0], r[1], r[2], 0.0f);
        }
    }
    // ---- directions for the 64 tile pixels (bit-exact resize of X + normalize) ----
    if (t < 64) {
        int qy = t >> 3, qx = t & 7;
        int h = ph0 + qy, w = pw0 + qx;
        int y0, y1, x0, x1; float wy, wx;
        ac_idx(h, HF, 127.0f / 63.0f, y0, y1, wy);
        ac_idx(w, WF, 415.0f / 207.0f, x0, x1, wx);
        float omwy = 1.0f - wy, omwx = 1.0f - wx;
        float d[3];
#pragma unroll
        for (int c = 0; c < 3; ++c) {
            const float* q = X + c * (HF * WF);
            float u00 = q[y0 * WF + x0], u10 = q[y1 * WF + x0];
            float u01 = q[y0 * WF + x1], u11 = q[y1 * WF + x1];
            float e0 = u00 * omwy; float f0 = u10 * wy; float s0 = e0 + f0;
            float e1 = u01 * omwy; float f1 = u11 * wy; float s1 = e1 + f1;
            float g0 = s0 * omwx; float g1 = s1 * wx;
            d[c] = g0 + g1;
        }
        float q0 = d[0] * d[0]; float q1 = d[1] * d[1]; float q2 = d[2] * d[2];
        float ssq = (q0 + q1) + q2;
        float nrm = (float)sqrt((double)ssq);   // correctly-rounded f32 sqrt
        dirs[t] = make_float4(d[0] / nrm, d[1] / nrm, d[2] / nrm, 0.0f);
    }
    if (t == 0) {
        double T64 = fmax(1e-8, 1e-4 / exp(0.1 * (double)prog[0]));
        Tsh = (float)T64;   // same bits as np.float32(max(1e-8, 1e-4/exp(...)))
    }
    __syncthreads();

    // ---- per-wave setup: 8 pixel directions in VGPRs, col window starts ----
    int h = ph0 + py;
    int srow_g = min(max(h - KH, 0), HS - 1 - 2 * KH);
    int I0 = srow_g - srow_min;            // 0..7
    float d0[8], d1[8], d2[8];
    int J0[8];
#pragma unroll
    for (int px = 0; px < 8; ++px) {
        float4 dv = dirs[py * 8 + px];
        d0[px] = dv.x; d1[px] = dv.y; d2[px] = dv.z;
        int w = pw0 + px;
        J0[px] = min(max(w - KH, 0), WS - 1 - 2 * KH) - scol_min;   // 0..7
    }
    float Tf = Tsh;

    // ---- pass 1: lane sweeps elements e = lane + 64*it over 41x48 row-union;
    //      each element: 1 LDS read, 8 bit-exact dots; running max + flag bit ----
    float m[8], mloc[8];
    unsigned msk[8];
#pragma unroll
    for (int px = 0; px < 8; ++px) { m[px] = -INFINITY; msk[px] = 0u; }
#pragma unroll
    for (int it = 0; it < NIT; ++it) {
        int e = lane + 64 * it;
        if (it < NIT - 1 || lane < GEL - 64 * (NIT - 1)) {
            int rho = (e * 683) >> 15;     // exact floor(e/48) for e < 2048
            int J = e - rho * TCOL;
            float4 v = tile[(I0 + rho) * PITCH + J];
#pragma unroll
            for (int px = 0; px < 8; ++px) {
                float p0 = d0[px] * v.x; float p1 = d1[px] * v.y; float p2 = d2[px] * v.z;
                float l = (p0 + p1) + p2;
                int c = J - J0[px];
                bool valid = (unsigned)c <= 40u;
                float lv = valid ? l : -INFINITY;
                bool f = lv > (m[px] - 0.004f);    // superset of final survivors
                msk[px] |= f ? (1u << it) : 0u;
                m[px] = fmaxf(m[px], lv);
            }
        }
    }
#pragma unroll
    for (int px = 0; px < 8; ++px) mloc[px] = m[px];
    // wave butterfly max -> all lanes hold the full-window max per px
#pragma unroll
    for (int s = 1; s < 64; s <<= 1) {
#pragma unroll
        for (int px = 0; px < 8; ++px) m[px] = fmaxf(m[px], __shfl_xor(m[px], s));
    }

    // ---- pass 2: ffs-walk flagged bits only; exact IEEE div + exp2 ----
    float se[8], sr[8], sc[8];
#pragma unroll
    for (int px = 0; px < 8; ++px) { se[px] = 0.f; sr[px] = 0.f; sc[px] = 0.f; }
#pragma unroll
    for (int px = 0; px < 8; ++px) {
        float th = m[px] - 0.004f;     // below: z-zm < -108 -> f32 weight exactly 0
        if (__ballot(mloc[px] > th)) {
            float zm = m[px] / Tf;     // monotone div: == ref's max-of-(l/T)
            unsigned w8 = (mloc[px] > th) ? msk[px] : 0u;
            while (w8) {
                int it = __ffs(w8) - 1;
                w8 &= w8 - 1;
                int e = lane + 64 * it;
                int rho = (e * 683) >> 15;
                int J = e - rho * TCOL;
                float4 v = tile[(I0 + rho) * PITCH + J];
                float p0 = d0[px] * v.x; float p1 = d1[px] * v.y; float p2 = d2[px] * v.z;
                float l = (p0 + p1) + p2;     // flagged => was valid (in-window)
                if (l > th) {
                    float z = l / Tf;         // bit-identical to ref's logits/T
                    float e2 = __builtin_amdgcn_exp2f((z - zm) * LOG2E);
                    se[px] += e2;
                    sr[px] += e2 * (float)(srow_g + rho);
                    sc[px] += e2 * (float)(scol_min + J);
                }
            }
        }
    }
    // butterfly sum; lane 0 then owns statically-indexed totals for all 8 px
#pragma unroll
    for (int s = 1; s < 64; s <<= 1) {
#pragma unroll
        for (int px = 0; px < 8; ++px) {
            se[px] += __shfl_xor(se[px], s);
            sr[px] += __shfl_xor(sr[px], s);
            sc[px] += __shfl_xor(sc[px], s);
        }
    }
    if (lane == 0) {
#pragma unroll
        for (int px = 0; px < 8; ++px) {
            int pix = h * WS + (pw0 + px);
            double ix = (double)sr[px] / (double)se[px];
            double iy = (double)sc[px] / (double)se[px];
            xn[pix] = (float)(2.0 * ix / (double)(HS - 1) - 1.0);
            yn[pix] = (float)(2.0 * iy / (double)(WS - 1) - 1.0);
        }
    }
}

// Bilinear upsample (align_corners) of (Yn, Xn) to full res, interleaved channels.
__global__ void k_up(const float* __restrict__ xn, const float* __restrict__ yn,
                     float* __restrict__ out) {
#pragma clang fp contract(off)
    int i = blockIdx.x * blockDim.x + threadIdx.x;
    if (i >= HF * WF) return;
    int hh = i / WF, ww = i - hh * WF;
    int y0, y1, x0, x1; float wy, wx;
    ac_idx(hh, HS, 63.0f / 127.0f, y0, y1, wy);
    ac_idx(ww, WS, 207.0f / 415.0f, x0, x1, wx);
    float omwy = 1.0f - wy, omwx = 1.0f - wx;
    float a0, b0, t0, t1;
    a0 = xn[y0 * WS + x0] * omwy; b0 = xn[y1 * WS + x0] * wy; t0 = a0 + b0;
    a0 = xn[y0 * WS + x1] * omwy; b0 = xn[y1 * WS + x1] * wy; t1 = a0 + b0;
    float bx = t0 * omwx + t1 * wx;     // Xn upsampled
    a0 = yn[y0 * WS + x0] * omwy; b0 = yn[y1 * WS + x0] * wy; t0 = a0 + b0;
    a0 = yn[y0 * WS + x1] * omwy; b0 = yn[y1 * WS + x1] * wy; t1 = a0 + b0;
    float ay = t0 * omwx + t1 * wx;     // Yn upsampled
    out[2 * i]     = ay;
    out[2 * i + 1] = bx;
}

extern "C" void kernel_launch(void* const* d_in, const int* in_sizes, int n_in,
                              void* d_out, int out_size, void* d_ws, size_t ws_size,
                              hipStream_t stream) {
    const float* R = (const float*)d_in[0];
    const float* X = (const float*)d_in[1];
    const int* prog = (const int*)d_in[2];
    float* xn = (float*)d_ws;        // NS
    float* yn = xn + NS;             // NS
    float* out = (float*)d_out;

    k_fused<<<NBLK, 512, 0, stream>>>(R, X, prog, xn, yn);
    k_up<<<(HF * WF + 255) / 256, 256, 0, stream>>>(xn, yn, out);
}